// Round 1
// baseline (395.963 us; speedup 1.0000x reference)
//
#include <hip/hip_runtime.h>
#include <hip/hip_bf16.h>

typedef __bf16 bf16x8 __attribute__((ext_vector_type(8)));
typedef float floatx4 __attribute__((ext_vector_type(4)));
typedef unsigned short ushort8 __attribute__((ext_vector_type(8)));
typedef unsigned short u16;

constexpr int T_DIM = 2048;
constexpr int H_DIM = 4096;
constexpr int O_DIM = 4096;
constexpr int R_DIM = 16;

// ---------------- fp32 -> bf16 (RNE) convert, 8 elems/thread ----------------
__device__ __forceinline__ u16 f2bf_rne(float f) {
  unsigned int u = __float_as_uint(f);
  u += 0x7fffu + ((u >> 16) & 1u);
  return (u16)(u >> 16);
}

__global__ __launch_bounds__(256) void cvt_bf16_kernel(const float* __restrict__ src,
                                                       ushort8* __restrict__ dst,
                                                       int n8) {
  int i = blockIdx.x * 256 + threadIdx.x;
  if (i >= n8) return;
  const float4* s4 = (const float4*)src;
  float4 a = s4[2 * i];
  float4 b = s4[2 * i + 1];
  ushort8 r;
  r[0] = f2bf_rne(a.x); r[1] = f2bf_rne(a.y); r[2] = f2bf_rne(a.z); r[3] = f2bf_rne(a.w);
  r[4] = f2bf_rne(b.x); r[5] = f2bf_rne(b.y); r[6] = f2bf_rne(b.z); r[7] = f2bf_rne(b.w);
  dst[i] = r;
}

// ---------------- per-token LoRA shrink: shrunk[t, r] = x[t,:] . A[l, r, :] ----------------
__global__ __launch_bounds__(256) void lora_shrink_kernel(const float* __restrict__ x,
                                                          const float* __restrict__ lora_a,
                                                          const int* __restrict__ idx,
                                                          float* __restrict__ shrunk) {
  const int t = blockIdx.x;
  const int tid = threadIdx.x;
  const int l = idx[t];
  if (l < 0) {
    if (tid < R_DIM) shrunk[t * R_DIM + tid] = 0.0f;
    return;
  }
  const float4* x4 = (const float4*)(x + (long)t * H_DIM);
  float4 xv[4];
#pragma unroll
  for (int i = 0; i < 4; ++i) xv[i] = x4[tid + i * 256];
  const float* Abase = lora_a + (long)l * R_DIM * H_DIM;
  float acc[R_DIM];
#pragma unroll
  for (int r = 0; r < R_DIM; ++r) {
    const float4* a4 = (const float4*)(Abase + r * H_DIM);
    float s = 0.f;
#pragma unroll
    for (int i = 0; i < 4; ++i) {
      float4 av = a4[tid + i * 256];
      s += xv[i].x * av.x + xv[i].y * av.y + xv[i].z * av.z + xv[i].w * av.w;
    }
    acc[r] = s;
  }
  __shared__ float red[4][R_DIM];
  const int lane = tid & 63, wave = tid >> 6;
#pragma unroll
  for (int r = 0; r < R_DIM; ++r) {
    float v = acc[r];
    v += __shfl_down(v, 32, 64);
    v += __shfl_down(v, 16, 64);
    v += __shfl_down(v, 8, 64);
    v += __shfl_down(v, 4, 64);
    v += __shfl_down(v, 2, 64);
    v += __shfl_down(v, 1, 64);
    if (lane == 0) red[wave][r] = v;
  }
  __syncthreads();
  if (tid < R_DIM)
    shrunk[t * R_DIM + tid] = red[0][tid] + red[1][tid] + red[2][tid] + red[3][tid];
}

// ---------------- async 16B global->LDS ----------------
__device__ __forceinline__ void async16(const u16* g, char* l) {
  __builtin_amdgcn_global_load_lds((const __attribute__((address_space(1))) unsigned int*)g,
                                   (__attribute__((address_space(3))) unsigned int*)l,
                                   16, 0, 0);
}

// ---------------- bf16 MFMA GEMM (B^T) + fused bias + LoRA expand epilogue ----------------
// Tile: BM=BN=128, BK=32. Block = 256 threads = 4 waves (2x2), each wave 64x64 via
// 4x4 grid of mfma_f32_16x16x32_bf16. m97 structure: global_load_lds w=16, 2-barrier K-loop.
__global__ __launch_bounds__(256) void gemm_lora_kernel(
    const u16* __restrict__ Abf,      // T x H bf16
    const u16* __restrict__ Bbf,      // O x H bf16 (W, row-major, K contiguous)
    const float* __restrict__ bias,   // O
    const float* __restrict__ shrunk, // T x R (zeros where idx < 0)
    const float* __restrict__ lora_b, // L x O x R
    const int* __restrict__ idx,      // T
    float* __restrict__ out) {        // T x O
  __shared__ __align__(16) char lds[2 * 128 * 32 * 2];  // A tile 8KB + B tile 8KB
  char* ldsA = lds;
  char* ldsB = lds + 128 * 32 * 2;

  const int tid = threadIdx.x;
  const int lane = tid & 63;
  const int wave = tid >> 6;
  const int wr = wave >> 1, wc = wave & 1;
  const int quad = lane >> 4, mn = lane & 15;

  const int t0 = blockIdx.y * 128;
  const int o0 = blockIdx.x * 128;

  // Staging: 512 chunks of 16B per tile; thread j covers (row = j>>2, col8 = (j&3)*8).
  // LDS addr = j*16 => per wave: uniform base + lane*16 (required by global_load_lds).
  const int j0 = tid, j1 = tid + 256;
  const u16* gA0 = Abf + (long)(t0 + (j0 >> 2)) * H_DIM + (j0 & 3) * 8;
  const u16* gA1 = Abf + (long)(t0 + (j1 >> 2)) * H_DIM + (j1 & 3) * 8;
  const u16* gB0 = Bbf + (long)(o0 + (j0 >> 2)) * H_DIM + (j0 & 3) * 8;
  const u16* gB1 = Bbf + (long)(o0 + (j1 >> 2)) * H_DIM + (j1 & 3) * 8;
  char* lA0 = ldsA + j0 * 16;
  char* lA1 = ldsA + j1 * 16;
  char* lB0 = ldsB + j0 * 16;
  char* lB1 = ldsB + j1 * 16;

  // Fragment pointers (constant over K): A[m=lane&15][k=quad*8+j], same for B rows.
  const char* apA[4];
  const char* apB[4];
#pragma unroll
  for (int i = 0; i < 4; ++i) {
    apA[i] = ldsA + ((wr * 64 + i * 16 + mn) * 32 + quad * 8) * 2;
    apB[i] = ldsB + ((wc * 64 + i * 16 + mn) * 32 + quad * 8) * 2;
  }

  floatx4 acc[4][4] = {};

  for (int k0 = 0; k0 < H_DIM; k0 += 32) {
    __syncthreads();  // all waves done reading previous tile
    async16(gA0 + k0, lA0);
    async16(gA1 + k0, lA1);
    async16(gB0 + k0, lB0);
    async16(gB1 + k0, lB1);
    __syncthreads();  // compiler drains vmcnt(0) before s_barrier

    bf16x8 af[4], bfr[4];
#pragma unroll
    for (int i = 0; i < 4; ++i) {
      af[i] = *(const bf16x8*)apA[i];
      bfr[i] = *(const bf16x8*)apB[i];
    }
#pragma unroll
    for (int i = 0; i < 4; ++i)
#pragma unroll
      for (int n = 0; n < 4; ++n)
        acc[i][n] = __builtin_amdgcn_mfma_f32_16x16x32_bf16(af[i], bfr[n], acc[i][n], 0, 0, 0);
  }

  // Epilogue. C/D layout (m89/m91): col = lane&15, row = quad*4 + reg.
  float bv[4];
#pragma unroll
  for (int n = 0; n < 4; ++n) bv[n] = bias[o0 + wc * 64 + n * 16 + mn];

#pragma unroll
  for (int i = 0; i < 4; ++i) {
#pragma unroll
    for (int r = 0; r < 4; ++r) {
      const int t = t0 + wr * 64 + i * 16 + quad * 4 + r;
      const int l = idx[t];
      const int ls = l < 0 ? 0 : l;  // shrunk rows are zero when l < 0 -> contribution 0
      const float4* sp = (const float4*)(shrunk + t * R_DIM);
      float4 s0 = sp[0], s1 = sp[1], s2 = sp[2], s3 = sp[3];
      float* orow = out + (long)t * O_DIM;
#pragma unroll
      for (int n = 0; n < 4; ++n) {
        const int o = o0 + wc * 64 + n * 16 + mn;
        const float4* bg = (const float4*)(lora_b + ((long)ls * O_DIM + o) * R_DIM);
        float4 b0 = bg[0], b1 = bg[1], b2 = bg[2], b3 = bg[3];
        float v = acc[i][n][r] + bv[n];
        v += s0.x * b0.x + s0.y * b0.y + s0.z * b0.z + s0.w * b0.w;
        v += s1.x * b1.x + s1.y * b1.y + s1.z * b1.z + s1.w * b1.w;
        v += s2.x * b2.x + s2.y * b2.y + s2.z * b2.z + s2.w * b2.w;
        v += s3.x * b3.x + s3.y * b3.y + s3.z * b3.z + s3.w * b3.w;
        orow[o] = v;
      }
    }
  }
}

extern "C" void kernel_launch(void* const* d_in, const int* in_sizes, int n_in,
                              void* d_out, int out_size, void* d_ws, size_t ws_size,
                              hipStream_t stream) {
  (void)in_sizes; (void)n_in; (void)out_size; (void)ws_size;
  const float* x      = (const float*)d_in[0];
  const float* w      = (const float*)d_in[1];
  const float* bias   = (const float*)d_in[2];
  const float* lora_a = (const float*)d_in[3];
  const float* lora_b = (const float*)d_in[4];
  const int*   idx    = (const int*)d_in[5];
  float* out = (float*)d_out;

  char* ws = (char*)d_ws;
  u16* xb = (u16*)ws;                                  // 16 MiB: T*H bf16
  u16* wb = (u16*)(ws + (size_t)16 * 1024 * 1024);     // 32 MiB: O*H bf16
  float* shrunk = (float*)(ws + (size_t)48 * 1024 * 1024);  // 128 KiB: T*R fp32

  cvt_bf16_kernel<<<T_DIM * H_DIM / 8 / 256, 256, 0, stream>>>(x, (ushort8*)xb, T_DIM * H_DIM / 8);
  cvt_bf16_kernel<<<O_DIM * H_DIM / 8 / 256, 256, 0, stream>>>(w, (ushort8*)wb, O_DIM * H_DIM / 8);
  lora_shrink_kernel<<<T_DIM, 256, 0, stream>>>(x, lora_a, idx, shrunk);

  dim3 grid(O_DIM / 128, T_DIM / 128);
  gemm_lora_kernel<<<grid, 256, 0, stream>>>(xb, wb, bias, shrunk, lora_b, idx, out);
}

// Round 2
// 384.535 us; speedup vs baseline: 1.0297x; 1.0297x over previous
//
#include <hip/hip_runtime.h>
#include <hip/hip_bf16.h>

typedef __bf16 bf16x8 __attribute__((ext_vector_type(8)));
typedef float floatx4 __attribute__((ext_vector_type(4)));
typedef unsigned short ushort8v __attribute__((ext_vector_type(8)));
typedef unsigned short u16;

constexpr int T_DIM = 2048;
constexpr int H_DIM = 4096;
constexpr int O_DIM = 4096;
constexpr int R_DIM = 16;
constexpr int L_DIM = 32;

// ---------------- fp32 -> bf16 (RNE) ----------------
__device__ __forceinline__ u16 f2bf_rne(float f) {
  unsigned int u = __float_as_uint(f);
  u += 0x7fffu + ((u >> 16) & 1u);
  return (u16)(u >> 16);
}

// one float4 -> ushort4 per thread; fully coalesced 16B loads / 8B stores
__global__ __launch_bounds__(256) void cvt_bf16_kernel(const float4* __restrict__ src,
                                                       ushort4* __restrict__ dst, int n4) {
  int i = blockIdx.x * 256 + threadIdx.x;
  if (i >= n4) return;
  float4 a = src[i];
  ushort4 r;
  r.x = f2bf_rne(a.x); r.y = f2bf_rne(a.y); r.z = f2bf_rne(a.z); r.w = f2bf_rne(a.w);
  dst[i] = r;
}

// ---------------- bucket tokens by lora index ----------------
// offs[33] prefix offsets, list[2048] token ids grouped by l.
// Also zeroes shrunk rows for idx<0 tokens (shrink kernel never touches them).
__global__ __launch_bounds__(256) void bucket_kernel(const int* __restrict__ idx,
                                                     int* __restrict__ offs,
                                                     int* __restrict__ list,
                                                     float* __restrict__ shrunk) {
  __shared__ int cnt[L_DIM];
  __shared__ int base_[L_DIM];
  __shared__ int cur[L_DIM];
  const int tid = threadIdx.x;
  if (tid < L_DIM) cnt[tid] = 0;
  __syncthreads();
  for (int t = tid; t < T_DIM; t += 256) {
    int l = idx[t];
    if (l >= 0) {
      atomicAdd(&cnt[l], 1);
    } else {
      float4 z = {0.f, 0.f, 0.f, 0.f};
      float4* s = (float4*)(shrunk + t * R_DIM);
      s[0] = z; s[1] = z; s[2] = z; s[3] = z;
    }
  }
  __syncthreads();
  if (tid == 0) {
    int acc = 0;
    for (int l = 0; l < L_DIM; ++l) { base_[l] = acc; acc += cnt[l]; }
  }
  __syncthreads();
  if (tid < L_DIM) {
    cur[tid] = 0;
    offs[tid] = base_[tid];
    if (tid == L_DIM - 1) offs[L_DIM] = base_[L_DIM - 1] + cnt[L_DIM - 1];
  }
  __syncthreads();
  for (int t = tid; t < T_DIM; t += 256) {
    int l = idx[t];
    if (l >= 0) {
      int p = base_[l] + atomicAdd(&cur[l], 1);
      list[p] = t;
    }
  }
}

// ---------------- MFMA shrink: per l, shrunk[tok, r] = x[tok,:] . A[l, r, :] ----------------
// One block per l (4 waves). Wave handles token-groups of 16 via mfma 16x16x32:
// A-operand = X rows (m = lane&15 -> token), B-operand = lora_a rows (n = lane&15 -> r).
// Fragments loaded straight from global (L2-hot); lora_a converted fp32->bf16 in-reg.
__global__ __launch_bounds__(256) void lora_shrink_mfma(const u16* __restrict__ xb,
                                                        const float* __restrict__ lora_a,
                                                        const int* __restrict__ offs,
                                                        const int* __restrict__ list,
                                                        float* __restrict__ shrunk) {
  const int l = blockIdx.x;
  const int off = offs[l];
  const int n = offs[l + 1] - off;
  if (n == 0) return;
  const int wave = threadIdx.x >> 6, lane = threadIdx.x & 63;
  const int quad = lane >> 4, mn = lane & 15;
  const int ngroups = (n + 15) / 16;
  const float* Ab = lora_a + (long)l * R_DIM * H_DIM;
  const float* arow = Ab + (long)mn * H_DIM + quad * 8;  // r = mn

  for (int g = wave; g < ngroups; g += 4) {
    int p = off + g * 16 + mn;
    int pc = off + n - 1;
    int tok = list[p < pc ? p : pc];  // clamp for partial groups
    const u16* xrow = xb + (long)tok * H_DIM + quad * 8;
    floatx4 acc = {0.f, 0.f, 0.f, 0.f};
#pragma unroll 4
    for (int k = 0; k < H_DIM; k += 32) {
      bf16x8 xf = *(const bf16x8*)(xrow + k);
      float4 a0 = *(const float4*)(arow + k);
      float4 a1 = *(const float4*)(arow + k + 4);
      ushort8v ar;
      ar[0] = f2bf_rne(a0.x); ar[1] = f2bf_rne(a0.y); ar[2] = f2bf_rne(a0.z); ar[3] = f2bf_rne(a0.w);
      ar[4] = f2bf_rne(a1.x); ar[5] = f2bf_rne(a1.y); ar[6] = f2bf_rne(a1.z); ar[7] = f2bf_rne(a1.w);
      acc = __builtin_amdgcn_mfma_f32_16x16x32_bf16(xf, __builtin_bit_cast(bf16x8, ar), acc, 0, 0, 0);
    }
    // C/D layout: col = lane&15 = r, row = quad*4 + reg = token-in-group
#pragma unroll
    for (int r = 0; r < 4; ++r) {
      int trow = g * 16 + quad * 4 + r;
      if (trow < n) shrunk[list[off + trow] * R_DIM + mn] = acc[r];
    }
  }
}

// ---------------- async 16B global->LDS ----------------
__device__ __forceinline__ void async16(const u16* g, char* l) {
  __builtin_amdgcn_global_load_lds((const __attribute__((address_space(1))) unsigned int*)g,
                                   (__attribute__((address_space(3))) unsigned int*)l,
                                   16, 0, 0);
}

// ---------------- bf16 MFMA GEMM (B^T), split-K partials, no epilogue ----------------
// 128x128x32 tile, 4 waves (2x2), wave = 64x64 via 4x4 mfma_f32_16x16x32_bf16.
// blockIdx.z selects K-half and destination (dest0 = out used as partial0).
__global__ __launch_bounds__(256) void gemm_kernel(const u16* __restrict__ Abf,
                                                   const u16* __restrict__ Bbf,
                                                   float* __restrict__ dest0,
                                                   float* __restrict__ dest1,
                                                   int klen) {
  __shared__ __align__(16) char lds[2 * 128 * 32 * 2];
  char* ldsA = lds;
  char* ldsB = lds + 128 * 32 * 2;

  const int tid = threadIdx.x;
  const int lane = tid & 63;
  const int wave = tid >> 6;
  const int wr = wave >> 1, wc = wave & 1;
  const int quad = lane >> 4, mn = lane & 15;

  const int t0 = blockIdx.y * 128;
  const int o0 = blockIdx.x * 128;
  const int kbase = blockIdx.z * klen;
  float* dest = blockIdx.z ? dest1 : dest0;

  const int j0 = tid, j1 = tid + 256;
  const u16* gA0 = Abf + (long)(t0 + (j0 >> 2)) * H_DIM + (j0 & 3) * 8 + kbase;
  const u16* gA1 = Abf + (long)(t0 + (j1 >> 2)) * H_DIM + (j1 & 3) * 8 + kbase;
  const u16* gB0 = Bbf + (long)(o0 + (j0 >> 2)) * H_DIM + (j0 & 3) * 8 + kbase;
  const u16* gB1 = Bbf + (long)(o0 + (j1 >> 2)) * H_DIM + (j1 & 3) * 8 + kbase;
  char* lA0 = ldsA + j0 * 16;
  char* lA1 = ldsA + j1 * 16;
  char* lB0 = ldsB + j0 * 16;
  char* lB1 = ldsB + j1 * 16;

  const char* apA[4];
  const char* apB[4];
#pragma unroll
  for (int i = 0; i < 4; ++i) {
    apA[i] = ldsA + ((wr * 64 + i * 16 + mn) * 32 + quad * 8) * 2;
    apB[i] = ldsB + ((wc * 64 + i * 16 + mn) * 32 + quad * 8) * 2;
  }

  floatx4 acc[4][4] = {};

  for (int k0 = 0; k0 < klen; k0 += 32) {
    __syncthreads();
    async16(gA0 + k0, lA0);
    async16(gA1 + k0, lA1);
    async16(gB0 + k0, lB0);
    async16(gB1 + k0, lB1);
    __syncthreads();

    bf16x8 af[4], bfr[4];
#pragma unroll
    for (int i = 0; i < 4; ++i) {
      af[i] = *(const bf16x8*)apA[i];
      bfr[i] = *(const bf16x8*)apB[i];
    }
#pragma unroll
    for (int i = 0; i < 4; ++i)
#pragma unroll
      for (int nn = 0; nn < 4; ++nn)
        acc[i][nn] = __builtin_amdgcn_mfma_f32_16x16x32_bf16(af[i], bfr[nn], acc[i][nn], 0, 0, 0);
  }

  // C/D layout: col = lane&15, row = quad*4 + reg
#pragma unroll
  for (int i = 0; i < 4; ++i) {
#pragma unroll
    for (int r = 0; r < 4; ++r) {
      const int t = t0 + wr * 64 + i * 16 + quad * 4 + r;
      float* orow = dest + (long)t * O_DIM;
#pragma unroll
      for (int nn = 0; nn < 4; ++nn)
        orow[o0 + wc * 64 + nn * 16 + mn] = acc[i][nn][r];
    }
  }
}

// ---------------- epilogue: out = part0(+part1) + bias + shrunk . B[l] ----------------
__global__ __launch_bounds__(256) void epilogue_kernel(float* __restrict__ out,
                                                       const float* __restrict__ part1,
                                                       const float* __restrict__ bias,
                                                       const float* __restrict__ shrunk,
                                                       const float* __restrict__ lora_b,
                                                       const int* __restrict__ idx,
                                                       int split) {
  const int t = blockIdx.y;
  const int o = (blockIdx.x * 256 + threadIdx.x) * 4;
  const int l = idx[t];
  const int ls = l < 0 ? 0 : l;  // shrunk row is zero when l<0
  const float4* sp = (const float4*)(shrunk + t * R_DIM);
  float4 s0 = sp[0], s1 = sp[1], s2 = sp[2], s3 = sp[3];

  float4 v = *(const float4*)(out + (long)t * O_DIM + o);
  if (split == 2) {
    float4 p = *(const float4*)(part1 + (long)t * O_DIM + o);
    v.x += p.x; v.y += p.y; v.z += p.z; v.w += p.w;
  }
  float4 bv = *(const float4*)(bias + o);
  v.x += bv.x; v.y += bv.y; v.z += bv.z; v.w += bv.w;

  const float4* bg = (const float4*)(lora_b + ((long)ls * O_DIM + o) * R_DIM);
  float* vp = &v.x;
#pragma unroll
  for (int j = 0; j < 4; ++j) {
    float4 b0 = bg[j * 4 + 0], b1 = bg[j * 4 + 1], b2 = bg[j * 4 + 2], b3 = bg[j * 4 + 3];
    float d = s0.x * b0.x + s0.y * b0.y + s0.z * b0.z + s0.w * b0.w;
    d += s1.x * b1.x + s1.y * b1.y + s1.z * b1.z + s1.w * b1.w;
    d += s2.x * b2.x + s2.y * b2.y + s2.z * b2.z + s2.w * b2.w;
    d += s3.x * b3.x + s3.y * b3.y + s3.z * b3.z + s3.w * b3.w;
    vp[j] += d;
  }
  *(float4*)(out + (long)t * O_DIM + o) = v;
}

extern "C" void kernel_launch(void* const* d_in, const int* in_sizes, int n_in,
                              void* d_out, int out_size, void* d_ws, size_t ws_size,
                              hipStream_t stream) {
  (void)in_sizes; (void)n_in; (void)out_size;
  const float* x      = (const float*)d_in[0];
  const float* w      = (const float*)d_in[1];
  const float* bias   = (const float*)d_in[2];
  const float* lora_a = (const float*)d_in[3];
  const float* lora_b = (const float*)d_in[4];
  const int*   idx    = (const int*)d_in[5];
  float* out = (float*)d_out;

  char* ws = (char*)d_ws;
  const size_t OFF_XB = 0;                                // 16 MiB
  const size_t OFF_WB = (size_t)16 << 20;                 // 32 MiB
  const size_t OFF_SHRUNK = (size_t)48 << 20;             // 128 KiB
  const size_t OFF_LIST = OFF_SHRUNK + 131072;            // 8 KiB
  const size_t OFF_OFFS = OFF_LIST + 8192;                // 132 B
  const size_t OFF_PART = (size_t)49 << 20;               // 32 MiB (split-K partial)
  const size_t NEED_SPLIT = OFF_PART + ((size_t)32 << 20);

  u16* xb = (u16*)(ws + OFF_XB);
  u16* wb = (u16*)(ws + OFF_WB);
  float* shrunk = (float*)(ws + OFF_SHRUNK);
  int* list = (int*)(ws + OFF_LIST);
  int* offs = (int*)(ws + OFF_OFFS);
  float* part1 = (float*)(ws + OFF_PART);

  const int split = (ws_size >= NEED_SPLIT) ? 2 : 1;
  const int klen = H_DIM / split;

  cvt_bf16_kernel<<<T_DIM * H_DIM / 4 / 256, 256, 0, stream>>>((const float4*)x, (ushort4*)xb, T_DIM * H_DIM / 4);
  cvt_bf16_kernel<<<O_DIM * H_DIM / 4 / 256, 256, 0, stream>>>((const float4*)w, (ushort4*)wb, O_DIM * H_DIM / 4);
  bucket_kernel<<<1, 256, 0, stream>>>(idx, offs, list, shrunk);
  lora_shrink_mfma<<<L_DIM, 256, 0, stream>>>(xb, lora_a, offs, list, shrunk);

  dim3 grid(O_DIM / 128, T_DIM / 128, split);
  gemm_kernel<<<grid, 256, 0, stream>>>(xb, wb, out, part1, klen);

  dim3 egrid(O_DIM / 1024, T_DIM);
  epilogue_kernel<<<egrid, 256, 0, stream>>>(out, part1, bias, shrunk, lora_b, idx, split);
}

// Round 3
// 350.212 us; speedup vs baseline: 1.1306x; 1.0980x over previous
//
#include <hip/hip_runtime.h>
#include <hip/hip_bf16.h>

typedef __bf16 bf16x8 __attribute__((ext_vector_type(8)));
typedef float floatx4 __attribute__((ext_vector_type(4)));
typedef unsigned short u16;

constexpr int T_DIM = 2048;
constexpr int H_DIM = 4096;
constexpr int O_DIM = 4096;
constexpr int R_DIM = 16;
constexpr int L_DIM = 32;

// ---------------- fp32 -> bf16 (RNE) ----------------
__device__ __forceinline__ u16 f2bf_rne(float f) {
  unsigned int u = __float_as_uint(f);
  u += 0x7fffu + ((u >> 16) & 1u);
  return (u16)(u >> 16);
}
__device__ __forceinline__ float bf2f(u16 h) {
  return __uint_as_float(((unsigned int)h) << 16);
}

__global__ __launch_bounds__(256) void cvt_bf16_kernel(const float4* __restrict__ src,
                                                       ushort4* __restrict__ dst, int n4) {
  int i = blockIdx.x * 256 + threadIdx.x;
  if (i >= n4) return;
  float4 a = src[i];
  ushort4 r;
  r.x = f2bf_rne(a.x); r.y = f2bf_rne(a.y); r.z = f2bf_rne(a.z); r.w = f2bf_rne(a.w);
  dst[i] = r;
}

// ---------------- bucket tokens by lora index; zero shrunk ----------------
__global__ __launch_bounds__(256) void bucket_kernel(const int* __restrict__ idx,
                                                     int* __restrict__ offs,
                                                     int* __restrict__ list,
                                                     float* __restrict__ shrunk) {
  __shared__ int cnt[L_DIM];
  __shared__ int base_[L_DIM];
  __shared__ int cur[L_DIM];
  const int tid = threadIdx.x;
  // zero all shrunk rows (shrink accumulates with atomics)
  float4 z = {0.f, 0.f, 0.f, 0.f};
  float4* s4 = (float4*)shrunk;
  for (int i = tid; i < T_DIM * R_DIM / 4; i += 256) s4[i] = z;
  if (tid < L_DIM) cnt[tid] = 0;
  __syncthreads();
  for (int t = tid; t < T_DIM; t += 256) {
    int l = idx[t];
    if (l >= 0) atomicAdd(&cnt[l], 1);
  }
  __syncthreads();
  if (tid == 0) {
    int acc = 0;
    for (int l = 0; l < L_DIM; ++l) { base_[l] = acc; acc += cnt[l]; }
  }
  __syncthreads();
  if (tid < L_DIM) {
    cur[tid] = 0;
    offs[tid] = base_[tid];
    if (tid == L_DIM - 1) offs[L_DIM] = base_[L_DIM - 1] + cnt[L_DIM - 1];
  }
  __syncthreads();
  for (int t = tid; t < T_DIM; t += 256) {
    int l = idx[t];
    if (l >= 0) {
      int p = base_[l] + atomicAdd(&cur[l], 1);
      list[p] = t;
    }
  }
}

// ---------------- MFMA shrink, split-K: shrunk[tok, r] += x[tok, kq] . A[l, r, kq] ----------------
// grid (L, 4). All-bf16 operands (ab pre-converted). atomicAdd into zeroed shrunk.
__global__ __launch_bounds__(256) void lora_shrink_mfma(const u16* __restrict__ xb,
                                                        const u16* __restrict__ ab,
                                                        const int* __restrict__ offs,
                                                        const int* __restrict__ list,
                                                        float* __restrict__ shrunk) {
  const int l = blockIdx.x;
  const int kbase = blockIdx.y * (H_DIM / 4);
  const int off = offs[l];
  const int n = offs[l + 1] - off;
  if (n == 0) return;
  const int wave = threadIdx.x >> 6, lane = threadIdx.x & 63;
  const int quad = lane >> 4, mn = lane & 15;
  const int ngroups = (n + 15) / 16;
  const u16* arow = ab + ((long)l * R_DIM + mn) * H_DIM + quad * 8 + kbase;  // r = mn

  for (int g = wave; g < ngroups; g += 4) {
    int p = off + g * 16 + mn;
    int pc = off + n - 1;
    int tok = list[p < pc ? p : pc];  // clamp for partial groups
    const u16* xrow = xb + (long)tok * H_DIM + quad * 8 + kbase;
    floatx4 acc = {0.f, 0.f, 0.f, 0.f};
#pragma unroll 4
    for (int k = 0; k < H_DIM / 4; k += 32) {
      bf16x8 xf = *(const bf16x8*)(xrow + k);
      bf16x8 af = *(const bf16x8*)(arow + k);
      acc = __builtin_amdgcn_mfma_f32_16x16x32_bf16(xf, af, acc, 0, 0, 0);
    }
    // C/D layout: col = lane&15 = r, row = quad*4 + reg = token-in-group
#pragma unroll
    for (int r = 0; r < 4; ++r) {
      int trow = g * 16 + quad * 4 + r;
      if (trow < n) atomicAdd(&shrunk[list[off + trow] * R_DIM + mn], acc[r]);
    }
  }
}

// ---------------- async 16B global->LDS ----------------
__device__ __forceinline__ void async16(const u16* g, char* l) {
  __builtin_amdgcn_global_load_lds((const __attribute__((address_space(1))) unsigned int*)g,
                                   (__attribute__((address_space(3))) unsigned int*)l,
                                   16, 0, 0);
}

// ---------------- bf16 MFMA GEMM (B^T), split-K, bf16 partials ----------------
// 128x128x32 tile, 4 waves (2x2). blockIdx.z selects K-chunk; partial -> parts + z*T*O.
__global__ __launch_bounds__(256) void gemm_kernel(const u16* __restrict__ Abf,
                                                   const u16* __restrict__ Bbf,
                                                   u16* __restrict__ parts,
                                                   int klen) {
  __shared__ __align__(16) char lds[2 * 128 * 32 * 2];
  char* ldsA = lds;
  char* ldsB = lds + 128 * 32 * 2;

  const int tid = threadIdx.x;
  const int lane = tid & 63;
  const int wave = tid >> 6;
  const int wr = wave >> 1, wc = wave & 1;
  const int quad = lane >> 4, mn = lane & 15;

  const int t0 = blockIdx.y * 128;
  const int o0 = blockIdx.x * 128;
  const int kbase = blockIdx.z * klen;
  u16* dest = parts + (long)blockIdx.z * T_DIM * O_DIM;

  const int j0 = tid, j1 = tid + 256;
  const u16* gA0 = Abf + (long)(t0 + (j0 >> 2)) * H_DIM + (j0 & 3) * 8 + kbase;
  const u16* gA1 = Abf + (long)(t0 + (j1 >> 2)) * H_DIM + (j1 & 3) * 8 + kbase;
  const u16* gB0 = Bbf + (long)(o0 + (j0 >> 2)) * H_DIM + (j0 & 3) * 8 + kbase;
  const u16* gB1 = Bbf + (long)(o0 + (j1 >> 2)) * H_DIM + (j1 & 3) * 8 + kbase;
  char* lA0 = ldsA + j0 * 16;
  char* lA1 = ldsA + j1 * 16;
  char* lB0 = ldsB + j0 * 16;
  char* lB1 = ldsB + j1 * 16;

  const char* apA[4];
  const char* apB[4];
#pragma unroll
  for (int i = 0; i < 4; ++i) {
    apA[i] = ldsA + ((wr * 64 + i * 16 + mn) * 32 + quad * 8) * 2;
    apB[i] = ldsB + ((wc * 64 + i * 16 + mn) * 32 + quad * 8) * 2;
  }

  floatx4 acc[4][4] = {};

  for (int k0 = 0; k0 < klen; k0 += 32) {
    __syncthreads();
    async16(gA0 + k0, lA0);
    async16(gA1 + k0, lA1);
    async16(gB0 + k0, lB0);
    async16(gB1 + k0, lB1);
    __syncthreads();

    bf16x8 af[4], bfr[4];
#pragma unroll
    for (int i = 0; i < 4; ++i) {
      af[i] = *(const bf16x8*)apA[i];
      bfr[i] = *(const bf16x8*)apB[i];
    }
#pragma unroll
    for (int i = 0; i < 4; ++i)
#pragma unroll
      for (int nn = 0; nn < 4; ++nn)
        acc[i][nn] = __builtin_amdgcn_mfma_f32_16x16x32_bf16(af[i], bfr[nn], acc[i][nn], 0, 0, 0);
  }

  // C/D layout: col = lane&15, row = quad*4 + reg. Store bf16 partials.
#pragma unroll
  for (int i = 0; i < 4; ++i) {
#pragma unroll
    for (int r = 0; r < 4; ++r) {
      const int t = t0 + wr * 64 + i * 16 + quad * 4 + r;
      u16* drow = dest + (long)t * O_DIM;
#pragma unroll
      for (int nn = 0; nn < 4; ++nn)
        drow[o0 + wc * 64 + nn * 16 + mn] = f2bf_rne(acc[i][nn][r]);
    }
  }
}

// ---------------- epilogue: out = p0(+p1) + bias + shrunk . B[l] ----------------
__global__ __launch_bounds__(256) void epilogue_kernel(float* __restrict__ out,
                                                       const u16* __restrict__ parts,
                                                       const float* __restrict__ bias,
                                                       const float* __restrict__ shrunk,
                                                       const float* __restrict__ lora_b,
                                                       const int* __restrict__ idx,
                                                       int split) {
  const int t = blockIdx.y;
  const int o = (blockIdx.x * 256 + threadIdx.x) * 4;
  const int l = idx[t];
  const int ls = l < 0 ? 0 : l;  // shrunk row is zero when l<0
  const float4* sp = (const float4*)(shrunk + t * R_DIM);
  float4 s0 = sp[0], s1 = sp[1], s2 = sp[2], s3 = sp[3];

  ushort4 p0 = *(const ushort4*)(parts + (long)t * O_DIM + o);
  float4 v = {bf2f(p0.x), bf2f(p0.y), bf2f(p0.z), bf2f(p0.w)};
  if (split == 2) {
    ushort4 p1 = *(const ushort4*)(parts + (long)T_DIM * O_DIM + (long)t * O_DIM + o);
    v.x += bf2f(p1.x); v.y += bf2f(p1.y); v.z += bf2f(p1.z); v.w += bf2f(p1.w);
  }
  float4 bv = *(const float4*)(bias + o);
  v.x += bv.x; v.y += bv.y; v.z += bv.z; v.w += bv.w;

  const float4* bg = (const float4*)(lora_b + ((long)ls * O_DIM + o) * R_DIM);
  float* vp = &v.x;
#pragma unroll
  for (int j = 0; j < 4; ++j) {
    float4 b0 = bg[j * 4 + 0], b1 = bg[j * 4 + 1], b2 = bg[j * 4 + 2], b3 = bg[j * 4 + 3];
    float d = s0.x * b0.x + s0.y * b0.y + s0.z * b0.z + s0.w * b0.w;
    d += s1.x * b1.x + s1.y * b1.y + s1.z * b1.z + s1.w * b1.w;
    d += s2.x * b2.x + s2.y * b2.y + s2.z * b2.z + s2.w * b2.w;
    d += s3.x * b3.x + s3.y * b3.y + s3.z * b3.z + s3.w * b3.w;
    vp[j] += d;
  }
  *(float4*)(out + (long)t * O_DIM + o) = v;
}

extern "C" void kernel_launch(void* const* d_in, const int* in_sizes, int n_in,
                              void* d_out, int out_size, void* d_ws, size_t ws_size,
                              hipStream_t stream) {
  (void)in_sizes; (void)n_in; (void)out_size;
  const float* x      = (const float*)d_in[0];
  const float* w      = (const float*)d_in[1];
  const float* bias   = (const float*)d_in[2];
  const float* lora_a = (const float*)d_in[3];
  const float* lora_b = (const float*)d_in[4];
  const int*   idx    = (const int*)d_in[5];
  float* out = (float*)d_out;

  char* ws = (char*)d_ws;
  const size_t OFF_XB = 0;                               // 16 MiB  x bf16
  const size_t OFF_WB = (size_t)16 << 20;                // 32 MiB  w bf16
  const size_t OFF_SHRUNK = (size_t)48 << 20;            // 128 KiB
  const size_t OFF_LIST = OFF_SHRUNK + 131072;           // 8 KiB
  const size_t OFF_OFFS = OFF_LIST + 8192;               // 132 B
  const size_t OFF_PARTS = (size_t)49 << 20;             // 16 MiB per K-chunk (bf16)
  // lora_a bf16 (4 MiB) overlaid on the parts region: written by cvt, consumed by
  // shrink, THEN clobbered by gemm partial stores — safe under stream ordering.
  const size_t OFF_AB = OFF_PARTS;
  const size_t NEED_SPLIT2 = OFF_PARTS + ((size_t)32 << 20);  // 81 MiB (proven available in R2)

  u16* xb = (u16*)(ws + OFF_XB);
  u16* wb = (u16*)(ws + OFF_WB);
  u16* ab = (u16*)(ws + OFF_AB);
  float* shrunk = (float*)(ws + OFF_SHRUNK);
  int* list = (int*)(ws + OFF_LIST);
  int* offs = (int*)(ws + OFF_OFFS);
  u16* parts = (u16*)(ws + OFF_PARTS);

  const int split = (ws_size >= NEED_SPLIT2) ? 2 : 1;
  const int klen = H_DIM / split;

  cvt_bf16_kernel<<<T_DIM * H_DIM / 4 / 256, 256, 0, stream>>>((const float4*)x, (ushort4*)xb, T_DIM * H_DIM / 4);
  cvt_bf16_kernel<<<O_DIM * H_DIM / 4 / 256, 256, 0, stream>>>((const float4*)w, (ushort4*)wb, O_DIM * H_DIM / 4);
  cvt_bf16_kernel<<<L_DIM * R_DIM * H_DIM / 4 / 256, 256, 0, stream>>>((const float4*)lora_a, (ushort4*)ab, L_DIM * R_DIM * H_DIM / 4);
  bucket_kernel<<<1, 256, 0, stream>>>(idx, offs, list, shrunk);
  lora_shrink_mfma<<<dim3(L_DIM, 4), 256, 0, stream>>>(xb, ab, offs, list, shrunk);

  dim3 grid(O_DIM / 128, T_DIM / 128, split);
  gemm_kernel<<<grid, 256, 0, stream>>>(xb, wb, parts, klen);

  dim3 egrid(O_DIM / 1024, T_DIM);
  epilogue_kernel<<<egrid, 256, 0, stream>>>(out, parts, bias, shrunk, lora_b, idx, split);
}

// Round 4
// 293.347 us; speedup vs baseline: 1.3498x; 1.1938x over previous
//
#include <hip/hip_runtime.h>
#include <hip/hip_bf16.h>

typedef __bf16 bf16x8 __attribute__((ext_vector_type(8)));
typedef float floatx4 __attribute__((ext_vector_type(4)));
typedef unsigned short u16;

constexpr int T_DIM = 2048;
constexpr int H_DIM = 4096;
constexpr int O_DIM = 4096;
constexpr int R_DIM = 16;
constexpr int L_DIM = 32;
constexpr int GSZ = 8;  // tokens per epilogue block

// ---------------- fp32 -> bf16 (RNE) ----------------
__device__ __forceinline__ u16 f2bf_rne(float f) {
  unsigned int u = __float_as_uint(f);
  u += 0x7fffu + ((u >> 16) & 1u);
  return (u16)(u >> 16);
}

// ---------------- fused convert: x, w, lora_a -> bf16 ----------------
__global__ __launch_bounds__(256) void cvt_all_kernel(const float4* __restrict__ x,
                                                      const float4* __restrict__ w,
                                                      const float4* __restrict__ a,
                                                      ushort4* __restrict__ xb,
                                                      ushort4* __restrict__ wb,
                                                      ushort4* __restrict__ ab) {
  const int NX = T_DIM * H_DIM / 4;
  const int NW = O_DIM * H_DIM / 4;
  const int NA = L_DIM * R_DIM * H_DIM / 4;
  int i = blockIdx.x * 256 + threadIdx.x;
  float4 v;
  ushort4* d;
  if (i < NX) { v = x[i]; d = xb + i; }
  else if (i < NX + NW) { v = w[i - NX]; d = wb + (i - NX); }
  else if (i < NX + NW + NA) { v = a[i - NX - NW]; d = ab + (i - NX - NW); }
  else return;
  ushort4 r;
  r.x = f2bf_rne(v.x); r.y = f2bf_rne(v.y); r.z = f2bf_rne(v.z); r.w = f2bf_rne(v.w);
  *d = r;
}

// ---------------- bucket: full token order (actives by l, inactives last); zero shrunk ----------------
__global__ __launch_bounds__(256) void bucket_kernel(const int* __restrict__ idx,
                                                     int* __restrict__ offs,
                                                     int* __restrict__ list,
                                                     float* __restrict__ shrunk) {
  __shared__ int cnt[L_DIM + 1];
  __shared__ int base_[L_DIM + 1];
  __shared__ int cur[L_DIM + 1];
  const int tid = threadIdx.x;
  float4 z = {0.f, 0.f, 0.f, 0.f};
  float4* s4 = (float4*)shrunk;
  for (int i = tid; i < T_DIM * R_DIM / 4; i += 256) s4[i] = z;
  if (tid <= L_DIM) cnt[tid] = 0;
  __syncthreads();
  for (int t = tid; t < T_DIM; t += 256) {
    int l = idx[t];
    atomicAdd(&cnt[l >= 0 ? l : L_DIM], 1);
  }
  __syncthreads();
  if (tid == 0) {
    int acc = 0;
    for (int l = 0; l <= L_DIM; ++l) { base_[l] = acc; acc += cnt[l]; }
  }
  __syncthreads();
  if (tid <= L_DIM) {
    cur[tid] = 0;
    offs[tid] = base_[tid];  // offs[32] = number of active tokens
  }
  __syncthreads();
  for (int t = tid; t < T_DIM; t += 256) {
    int l = idx[t];
    int b = l >= 0 ? l : L_DIM;
    int p = base_[b] + atomicAdd(&cur[b], 1);
    list[p] = t;
  }
}

// ---------------- MFMA shrink, split-K: shrunk[tok, r] += x[tok, kq] . A[l, r, kq] ----------------
__global__ __launch_bounds__(256) void lora_shrink_mfma(const u16* __restrict__ xb,
                                                        const u16* __restrict__ ab,
                                                        const int* __restrict__ offs,
                                                        const int* __restrict__ list,
                                                        float* __restrict__ shrunk) {
  const int l = blockIdx.x;
  const int kbase = blockIdx.y * (H_DIM / 4);
  const int off = offs[l];
  const int n = offs[l + 1] - off;
  if (n == 0) return;
  const int wave = threadIdx.x >> 6, lane = threadIdx.x & 63;
  const int quad = lane >> 4, mn = lane & 15;
  const int ngroups = (n + 15) / 16;
  const u16* arow = ab + ((long)l * R_DIM + mn) * H_DIM + quad * 8 + kbase;  // r = mn

  for (int g = wave; g < ngroups; g += 4) {
    int p = off + g * 16 + mn;
    int pc = off + n - 1;
    int tok = list[p < pc ? p : pc];
    const u16* xrow = xb + (long)tok * H_DIM + quad * 8 + kbase;
    floatx4 acc = {0.f, 0.f, 0.f, 0.f};
#pragma unroll 4
    for (int k = 0; k < H_DIM / 4; k += 32) {
      bf16x8 xf = *(const bf16x8*)(xrow + k);
      bf16x8 af = *(const bf16x8*)(arow + k);
      acc = __builtin_amdgcn_mfma_f32_16x16x32_bf16(xf, af, acc, 0, 0, 0);
    }
#pragma unroll
    for (int r = 0; r < 4; ++r) {
      int trow = g * 16 + quad * 4 + r;
      if (trow < n) atomicAdd(&shrunk[list[off + trow] * R_DIM + mn], acc[r]);
    }
  }
}

// ---------------- async 16B global->LDS ----------------
__device__ __forceinline__ void async16(const u16* g, char* l) {
  __builtin_amdgcn_global_load_lds((const __attribute__((address_space(1))) unsigned int*)g,
                                   (__attribute__((address_space(3))) unsigned int*)l,
                                   16, 0, 0);
}

// ---------------- bf16 MFMA GEMM (B^T), split-K=2, fp32 partials (R2 config) ----------------
__global__ __launch_bounds__(256) void gemm_kernel(const u16* __restrict__ Abf,
                                                   const u16* __restrict__ Bbf,
                                                   float* __restrict__ dest0,
                                                   float* __restrict__ dest1,
                                                   int klen) {
  __shared__ __align__(16) char lds[2 * 128 * 32 * 2];
  char* ldsA = lds;
  char* ldsB = lds + 128 * 32 * 2;

  const int tid = threadIdx.x;
  const int lane = tid & 63;
  const int wave = tid >> 6;
  const int wr = wave >> 1, wc = wave & 1;
  const int quad = lane >> 4, mn = lane & 15;

  const int t0 = blockIdx.y * 128;
  const int o0 = blockIdx.x * 128;
  const int kbase = blockIdx.z * klen;
  float* dest = blockIdx.z ? dest1 : dest0;

  const int j0 = tid, j1 = tid + 256;
  const u16* gA0 = Abf + (long)(t0 + (j0 >> 2)) * H_DIM + (j0 & 3) * 8 + kbase;
  const u16* gA1 = Abf + (long)(t0 + (j1 >> 2)) * H_DIM + (j1 & 3) * 8 + kbase;
  const u16* gB0 = Bbf + (long)(o0 + (j0 >> 2)) * H_DIM + (j0 & 3) * 8 + kbase;
  const u16* gB1 = Bbf + (long)(o0 + (j1 >> 2)) * H_DIM + (j1 & 3) * 8 + kbase;
  char* lA0 = ldsA + j0 * 16;
  char* lA1 = ldsA + j1 * 16;
  char* lB0 = ldsB + j0 * 16;
  char* lB1 = ldsB + j1 * 16;

  const char* apA[4];
  const char* apB[4];
#pragma unroll
  for (int i = 0; i < 4; ++i) {
    apA[i] = ldsA + ((wr * 64 + i * 16 + mn) * 32 + quad * 8) * 2;
    apB[i] = ldsB + ((wc * 64 + i * 16 + mn) * 32 + quad * 8) * 2;
  }

  floatx4 acc[4][4] = {};

  for (int k0 = 0; k0 < klen; k0 += 32) {
    __syncthreads();
    async16(gA0 + k0, lA0);
    async16(gA1 + k0, lA1);
    async16(gB0 + k0, lB0);
    async16(gB1 + k0, lB1);
    __syncthreads();

    bf16x8 af[4], bfr[4];
#pragma unroll
    for (int i = 0; i < 4; ++i) {
      af[i] = *(const bf16x8*)apA[i];
      bfr[i] = *(const bf16x8*)apB[i];
    }
#pragma unroll
    for (int i = 0; i < 4; ++i)
#pragma unroll
      for (int nn = 0; nn < 4; ++nn)
        acc[i][nn] = __builtin_amdgcn_mfma_f32_16x16x32_bf16(af[i], bfr[nn], acc[i][nn], 0, 0, 0);
  }

  // C/D layout: col = lane&15, row = quad*4 + reg
#pragma unroll
  for (int i = 0; i < 4; ++i) {
#pragma unroll
    for (int r = 0; r < 4; ++r) {
      const int t = t0 + wr * 64 + i * 16 + quad * 4 + r;
      float* orow = dest + (long)t * O_DIM;
#pragma unroll
      for (int nn = 0; nn < 4; ++nn)
        orow[o0 + wc * 64 + nn * 16 + mn] = acc[i][nn][r];
    }
  }
}

// ---------------- epilogue v2: token-grouped, B cached in regs ----------------
// block = (o-chunk of 1024, group of GSZ tokens from sorted list). B[l] chunk
// (4 o x 16 r per thread = 64 regs) reloaded only when l changes (block-uniform).
__global__ __launch_bounds__(256) void epilogue_kernel(float* __restrict__ out,
                                                       const float* __restrict__ part1,
                                                       const float* __restrict__ bias,
                                                       const float* __restrict__ shrunk,
                                                       const float* __restrict__ lora_b,
                                                       const int* __restrict__ idx,
                                                       const int* __restrict__ list,
                                                       int split) {
  const int o = blockIdx.x * 1024 + threadIdx.x * 4;
  const int g0 = blockIdx.y * GSZ;
  float4 bv = *(const float4*)(bias + o);
  float4 B[4][4];
  int lcur = -1;
#pragma unroll
  for (int gi = 0; gi < GSZ; ++gi) {
    const int t = list[g0 + gi];
    const int l = idx[t];
    const int ls = l < 0 ? 0 : l;  // shrunk row is zero when l<0 -> dot = 0
    if (ls != lcur) {
      lcur = ls;
      const float4* bg = (const float4*)(lora_b + ((long)ls * O_DIM + o) * R_DIM);
#pragma unroll
      for (int j = 0; j < 4; ++j)
#pragma unroll
        for (int q = 0; q < 4; ++q) B[j][q] = bg[j * 4 + q];
    }
    const float4* sp = (const float4*)(shrunk + t * R_DIM);
    float4 s0 = sp[0], s1 = sp[1], s2 = sp[2], s3 = sp[3];
    float4 v = *(const float4*)(out + (long)t * O_DIM + o);
    if (split == 2) {
      float4 p = *(const float4*)(part1 + (long)t * O_DIM + o);
      v.x += p.x; v.y += p.y; v.z += p.z; v.w += p.w;
    }
    v.x += bv.x; v.y += bv.y; v.z += bv.z; v.w += bv.w;
    float* vp = &v.x;
#pragma unroll
    for (int j = 0; j < 4; ++j) {
      float d = s0.x * B[j][0].x + s0.y * B[j][0].y + s0.z * B[j][0].z + s0.w * B[j][0].w;
      d += s1.x * B[j][1].x + s1.y * B[j][1].y + s1.z * B[j][1].z + s1.w * B[j][1].w;
      d += s2.x * B[j][2].x + s2.y * B[j][2].y + s2.z * B[j][2].z + s2.w * B[j][2].w;
      d += s3.x * B[j][3].x + s3.y * B[j][3].y + s3.z * B[j][3].z + s3.w * B[j][3].w;
      vp[j] += d;
    }
    *(float4*)(out + (long)t * O_DIM + o) = v;
  }
}

extern "C" void kernel_launch(void* const* d_in, const int* in_sizes, int n_in,
                              void* d_out, int out_size, void* d_ws, size_t ws_size,
                              hipStream_t stream) {
  (void)in_sizes; (void)n_in; (void)out_size;
  const float* x      = (const float*)d_in[0];
  const float* w      = (const float*)d_in[1];
  const float* bias   = (const float*)d_in[2];
  const float* lora_a = (const float*)d_in[3];
  const float* lora_b = (const float*)d_in[4];
  const int*   idx    = (const int*)d_in[5];
  float* out = (float*)d_out;

  char* ws = (char*)d_ws;
  const size_t OFF_XB = 0;                               // 16 MiB  x bf16
  const size_t OFF_WB = (size_t)16 << 20;                // 32 MiB  w bf16
  const size_t OFF_SHRUNK = (size_t)48 << 20;            // 128 KiB
  const size_t OFF_LIST = OFF_SHRUNK + 131072;           // 8 KiB
  const size_t OFF_OFFS = OFF_LIST + 8192;               // 136 B
  const size_t OFF_PART = (size_t)49 << 20;              // 32 MiB fp32 partial1
  // lora_a bf16 (4 MiB) overlaid on partial1: written by cvt, consumed by shrink,
  // then clobbered by gemm partial stores — safe under stream ordering.
  const size_t OFF_AB = OFF_PART;
  const size_t NEED_SPLIT2 = OFF_PART + ((size_t)32 << 20);  // 81 MiB (proven in R2)

  u16* xb = (u16*)(ws + OFF_XB);
  u16* wb = (u16*)(ws + OFF_WB);
  u16* ab = (u16*)(ws + OFF_AB);
  float* shrunk = (float*)(ws + OFF_SHRUNK);
  int* list = (int*)(ws + OFF_LIST);
  int* offs = (int*)(ws + OFF_OFFS);
  float* part1 = (float*)(ws + OFF_PART);

  const int split = (ws_size >= NEED_SPLIT2) ? 2 : 1;
  const int klen = H_DIM / split;

  const int NCVT = (T_DIM * H_DIM + O_DIM * H_DIM + L_DIM * R_DIM * H_DIM) / 4;
  cvt_all_kernel<<<NCVT / 256, 256, 0, stream>>>((const float4*)x, (const float4*)w,
                                                 (const float4*)lora_a,
                                                 (ushort4*)xb, (ushort4*)wb, (ushort4*)ab);
  bucket_kernel<<<1, 256, 0, stream>>>(idx, offs, list, shrunk);
  lora_shrink_mfma<<<dim3(L_DIM, 4), 256, 0, stream>>>(xb, ab, offs, list, shrunk);

  dim3 grid(O_DIM / 128, T_DIM / 128, split);
  gemm_kernel<<<grid, 256, 0, stream>>>(xb, wb, out, part1, klen);

  dim3 egrid(O_DIM / 1024, T_DIM / GSZ);
  epilogue_kernel<<<egrid, 256, 0, stream>>>(out, part1, bias, shrunk, lora_b, idx, list, split);
}